// Round 1
// baseline (1030.393 us; speedup 1.0000x reference)
//
#include <hip/hip_runtime.h>

typedef __attribute__((ext_vector_type(8))) unsigned short us8;
typedef __attribute__((ext_vector_type(4))) unsigned short us4;
typedef __attribute__((ext_vector_type(2))) unsigned short us2;
typedef __attribute__((ext_vector_type(8))) short s8;
typedef __attribute__((ext_vector_type(4))) float f4;

#define DEV static __device__ __forceinline__

DEV float bf2f(unsigned short h){ return __uint_as_float(((unsigned)h)<<16); }
DEV unsigned short f2bf(float f){
  unsigned x = __float_as_uint(f);
  x += 0x7fffu + ((x>>16)&1u);
  return (unsigned short)(x>>16);
}
DEV float sigm(float x){ return 1.f/(1.f + __expf(-x)); }

// ---------------- setup kernels ----------------
__global__ void k_zero_int(int* p, int n){
  int i = blockIdx.x*blockDim.x+threadIdx.x; if(i<n) p[i]=0;
}

__global__ void k_hist(const int* __restrict__ dst, int* __restrict__ degi, int e){
  int i = blockIdx.x*blockDim.x+threadIdx.x;
  if(i<e) atomicAdd(&degi[dst[i]], 1);
}

__global__ void k_dinv(const int* __restrict__ degi, float* __restrict__ dinv, int n){
  int i = blockIdx.x*blockDim.x+threadIdx.x;
  if(i<n) dinv[i] = rsqrtf((float)degi[i] + 1.0f);
}

__global__ void k_scan_part(const int* __restrict__ deg, int* __restrict__ rowp,
                            int* __restrict__ part, int n){
  __shared__ int sd[256];
  int t = threadIdx.x, blk = blockIdx.x;
  int base = blk*1024 + t*4;
  int v[4], tot = 0;
  #pragma unroll
  for(int j=0;j<4;++j){ v[j] = (base+j<n) ? deg[base+j] : 0; tot += v[j]; }
  sd[t] = tot; __syncthreads();
  for(int off=1; off<256; off<<=1){
    int x = (t>=off) ? sd[t-off] : 0;
    __syncthreads();
    sd[t] += x;
    __syncthreads();
  }
  int excl = sd[t] - tot;
  if(t==255) part[blk] = sd[t];
  int run = excl;
  #pragma unroll
  for(int j=0;j<4;++j){ if(base+j<n) rowp[base+j] = run; run += v[j]; }
}

__global__ void k_scan_top(int* part, int nb){
  if(threadIdx.x==0 && blockIdx.x==0){
    int run = 0;
    for(int i=0;i<nb;++i){ int v = part[i]; part[i] = run; run += v; }
  }
}

__global__ void k_scan_add(int* __restrict__ rowp, const int* __restrict__ part, int n){
  int blk = blockIdx.x, t = threadIdx.x;
  int add = part[blk];
  int base = blk*1024 + t*4;
  #pragma unroll
  for(int j=0;j<4;++j) if(base+j<n) rowp[base+j] += add;
}

__global__ void k_fill(const int* __restrict__ src, const int* __restrict__ dst,
                       const int* __restrict__ rowp, int* __restrict__ cnt,
                       int* __restrict__ col, int e){
  int i = blockIdx.x*blockDim.x+threadIdx.x;
  if(i<e){
    int d = dst[i];
    int pos = rowp[d] + atomicAdd(&cnt[d],1);
    col[pos] = src[i];
  }
}

// transpose + bf16-cast the 12 weight matrices: WT[m][j][k] = W[m][k][j]
__global__ void k_prepw(const float* __restrict__ Wx, const float* __restrict__ Wh,
                        unsigned short* __restrict__ WT, int total){
  int i = blockIdx.x*blockDim.x+threadIdx.x;
  if(i>=total) return;
  int m = i >> 14;
  int rem = i & 16383;
  int j = rem >> 7;     // output column
  int k = rem & 127;    // k index
  const float* W = (m<6) ? (Wx + (size_t)m*16384) : (Wh + (size_t)(m-6)*16384);
  WT[(size_t)m*16384 + rem] = f2bf(W[(size_t)k*128 + j]);
}

// ---------------- per-layer kernels ----------------
// y2[n,0:128] = bf16(dinv[n]*inp[n]);  y2[n,128:256] = bf16(dinv[n]*h_l[n])
__global__ void k_scale2(const float* __restrict__ inp, const float* __restrict__ hl,
                         const float* __restrict__ dinv, unsigned short* __restrict__ y2, int n){
  int i = blockIdx.x*blockDim.x+threadIdx.x;
  if(i >= n*32) return;
  int node = i>>5, d0 = (i&31)*4;
  float dv = dinv[node];
  f4 a = *(const f4*)(inp + (size_t)node*128 + d0);
  f4 b = *(const f4*)(hl  + (size_t)node*128 + d0);
  us4 wa, wb;
  #pragma unroll
  for(int j=0;j<4;++j){ wa[j] = f2bf(dv*a[j]); wb[j] = f2bf(dv*b[j]); }
  *(us4*)(y2 + (size_t)node*256 + d0)       = wa;
  *(us4*)(y2 + (size_t)node*256 + 128 + d0) = wb;
}

// CSR aggregation: out = bf16( dinv[n] * ( y[n] + sum_{src->n} y[src] ) )
// NV = bf16 elems per lane (2 -> D=128, 4 -> D=256 split into out0/out1)
template<int NV>
__global__ __launch_bounds__(256) void k_agg(const unsigned short* __restrict__ y,
    const int* __restrict__ rowp, const int* __restrict__ degi, const int* __restrict__ col,
    const float* __restrict__ dinv, unsigned short* __restrict__ out0,
    unsigned short* __restrict__ out1, int n)
{
  constexpr int D = NV*64;
  int lane = threadIdx.x & 63;
  int node = blockIdx.x*4 + (threadIdx.x>>6);
  if(node >= n) return;
  float acc[NV];
  {
    const unsigned short* p = y + (size_t)node*D + lane*NV;
    if constexpr(NV==2){ us2 v = *(const us2*)p; acc[0]=bf2f(v[0]); acc[1]=bf2f(v[1]); }
    else { us4 v = *(const us4*)p;
      #pragma unroll
      for(int j=0;j<4;++j) acc[j]=bf2f(v[j]); }
  }
  int start = rowp[node];
  int cnt = degi[node];
  for(int i=0;i<cnt;++i){
    int s = col[start+i];
    const unsigned short* p = y + (size_t)s*D + lane*NV;
    if constexpr(NV==2){ us2 v = *(const us2*)p; acc[0]+=bf2f(v[0]); acc[1]+=bf2f(v[1]); }
    else { us4 v = *(const us4*)p;
      #pragma unroll
      for(int j=0;j<4;++j) acc[j]+=bf2f(v[j]); }
  }
  float dv = dinv[node];
  if constexpr(NV==2){
    us2 w; w[0]=f2bf(acc[0]*dv); w[1]=f2bf(acc[1]*dv);
    *(us2*)(out0 + (size_t)node*128 + lane*2) = w;
  } else {
    us4 w;
    #pragma unroll
    for(int j=0;j<4;++j) w[j]=f2bf(acc[j]*dv);
    int c = lane*4;
    unsigned short* o = (c<128) ? (out0 + (size_t)node*128 + c)
                                : (out1 + (size_t)node*128 + (c-128));
    *(us4*)o = w;
  }
}

// C[brow:brow+128, 0:128] (+)= A1@B1 (+ A2@B2), bf16 MFMA, fp32 out, ldc stride.
__global__ __launch_bounds__(256) void k_gemm(const unsigned short* __restrict__ A1,
    const unsigned short* __restrict__ A2, const unsigned short* __restrict__ B1,
    const unsigned short* __restrict__ B2, float* __restrict__ C, int ldc, int nrows, int accum)
{
  __shared__ unsigned short As[128*136];
  __shared__ unsigned short Bs[128*136];
  const int t = threadIdx.x;
  const int lane = t & 63;
  const int lo = lane & 15, hi = lane >> 4;
  const int wid = t >> 6;
  const int wr = wid >> 1, wc = wid & 1;
  const int brow = blockIdx.x * 128;
  f4 acc[4][4];
  #pragma unroll
  for(int m=0;m<4;++m)
    #pragma unroll
    for(int n=0;n<4;++n) acc[m][n] = (f4)0.f;

  const int nch = A2 ? 2 : 1;
  for(int ch=0; ch<nch; ++ch){
    const unsigned short* A = ch ? A2 : A1;
    const unsigned short* B = ch ? B2 : B1;
    __syncthreads();
    #pragma unroll
    for(int i=0;i<8;++i){
      int c = t + i*256;          // 0..2047 chunks of 8 bf16
      int r = c >> 4, k0 = (c & 15)*8;
      us8 va = (us8)0;
      int gr = brow + r;
      if (gr < nrows) va = *(const us8*)(A + (size_t)gr*128 + k0);
      *(us8*)(&As[r*136 + k0]) = va;
      us8 vb = *(const us8*)(B + (size_t)c*8);
      *(us8*)(&Bs[r*136 + k0]) = vb;
    }
    __syncthreads();
    #pragma unroll
    for(int kk=0;kk<4;++kk){
      s8 af[4], bfr[4];
      #pragma unroll
      for(int m=0;m<4;++m)
        af[m] = *(const s8*)(&As[(wr*64 + m*16 + lo)*136 + kk*32 + hi*8]);
      #pragma unroll
      for(int n=0;n<4;++n)
        bfr[n] = *(const s8*)(&Bs[(wc*64 + n*16 + lo)*136 + kk*32 + hi*8]);
      #pragma unroll
      for(int m=0;m<4;++m)
        #pragma unroll
        for(int n=0;n<4;++n)
          acc[m][n] = __builtin_amdgcn_mfma_f32_16x16x32_bf16(af[m], bfr[n], acc[m][n], 0,0,0);
    }
  }

  const int c0 = wc*64;
  #pragma unroll
  for(int m=0;m<4;++m){
    int rbase = brow + wr*64 + m*16 + hi*4;
    #pragma unroll
    for(int n=0;n<4;++n){
      int colv = c0 + n*16 + lo;
      #pragma unroll
      for(int tt=0;tt<4;++tt){
        int row = rbase + tt;
        if(row < nrows){
          size_t off = (size_t)row*ldc + colv;
          float v = acc[m][n][tt];
          if(accum) v += C[off];
          C[off] = v;
        }
      }
    }
  }
}

// yq = bf16( dinv * sigmoid(rpre + bxr + bhr) * h_l )
__global__ void k_zr(const float* __restrict__ Zpre, const float* __restrict__ bxr,
                     const float* __restrict__ bhr, const float* __restrict__ hl,
                     const float* __restrict__ dinv, unsigned short* __restrict__ yq, int n){
  int i = blockIdx.x*blockDim.x+threadIdx.x;
  if(i >= n*32) return;
  int node = i>>5, d0 = (i&31)*4;
  f4 rp = *(const f4*)(Zpre + (size_t)node*384 + 128 + d0);
  f4 hh = *(const f4*)(hl + (size_t)node*128 + d0);
  float dv = dinv[node];
  us4 w;
  #pragma unroll
  for(int j=0;j<4;++j){
    float r = sigm(rp[j] + bxr[d0+j] + bhr[d0+j]);
    w[j] = f2bf(dv * r * hh[j]);
  }
  *(us4*)(yq + (size_t)node*128 + d0) = w;
}

// out = z*h + (1-z)*tanh(htpre),  z = sigmoid(zpre)
__global__ void k_final(const float* __restrict__ Zpre, const float* __restrict__ bx0,
                        const float* __restrict__ bh0, const float* __restrict__ bx2,
                        const float* __restrict__ bh2, const float* __restrict__ hl,
                        float* __restrict__ out, int n){
  int i = blockIdx.x*blockDim.x+threadIdx.x;
  if(i >= n*32) return;
  int node = i>>5, d0 = (i&31)*4;
  f4 zp = *(const f4*)(Zpre + (size_t)node*384 + d0);
  f4 hp = *(const f4*)(Zpre + (size_t)node*384 + 256 + d0);
  f4 hh = *(const f4*)(hl + (size_t)node*128 + d0);
  f4 o;
  #pragma unroll
  for(int j=0;j<4;++j){
    float z  = sigm(zp[j] + bx0[d0+j] + bh0[d0+j]);
    float ht = tanhf(hp[j] + bx2[d0+j] + bh2[d0+j]);
    o[j] = z*hh[j] + (1.f - z)*ht;
  }
  *(f4*)(out + (size_t)node*128 + d0) = o;
}

extern "C" void kernel_launch(void* const* d_in, const int* in_sizes, int n_in,
                              void* d_out, int out_size, void* d_ws, size_t ws_size,
                              hipStream_t stream){
  const float* x  = (const float*)d_in[0];
  const int*   ei = (const int*)d_in[1];
  const float* h  = (const float*)d_in[2];
  const float* Wx = (const float*)d_in[3];
  const float* bx = (const float*)d_in[4];
  const float* Wh = (const float*)d_in[5];
  const float* bh = (const float*)d_in[6];
  float* out = (float*)d_out;

  const int N = in_sizes[0] / 128;
  const int E = in_sizes[1] / 2;
  const int L = in_sizes[2] / in_sizes[0];
  const int* src = ei;
  const int* dst = ei + E;

  char* w = (char*)d_ws;
  auto alloc = [&](size_t b)->char*{ char* p = w; w += (b + 255) & ~(size_t)255; return p; };
  int* degi = (int*)alloc((size_t)2*N*sizeof(int)); int* cnt = degi + N;
  int* rowp = (int*)alloc((size_t)N*sizeof(int));
  int* part = (int*)alloc(256*sizeof(int));
  int* col  = (int*)alloc((size_t)E*sizeof(int));
  float* dinv = (float*)alloc((size_t)N*sizeof(float));
  unsigned short* WT = (unsigned short*)alloc((size_t)12*16384*sizeof(short));
  unsigned short* y2 = (unsigned short*)alloc((size_t)N*256*sizeof(short));
  unsigned short* ax = (unsigned short*)alloc((size_t)N*128*sizeof(short));
  unsigned short* ah = (unsigned short*)alloc((size_t)N*128*sizeof(short));
  unsigned short* yq = (unsigned short*)alloc((size_t)N*128*sizeof(short));
  unsigned short* aq = (unsigned short*)alloc((size_t)N*128*sizeof(short));
  float* Zpre = (float*)alloc((size_t)N*384*sizeof(float));

  const int NB = (N + 1023)/1024;
  const int gE = (E + 255)/256;
  const int gN = (N + 255)/256;
  const int gew = (N*32 + 255)/256;
  const int gagg = (N + 3)/4;
  const int grows = (N + 127)/128;

  k_zero_int<<<(2*N+255)/256,256,0,stream>>>(degi, 2*N);
  k_hist<<<gE,256,0,stream>>>(dst, degi, E);
  k_dinv<<<gN,256,0,stream>>>(degi, dinv, N);
  k_scan_part<<<NB,256,0,stream>>>(degi, rowp, part, N);
  k_scan_top<<<1,64,0,stream>>>(part, NB);
  k_scan_add<<<NB,256,0,stream>>>(rowp, part, N);
  k_fill<<<gE,256,0,stream>>>(src, dst, rowp, cnt, col, E);
  k_prepw<<<(12*16384+255)/256,256,0,stream>>>(Wx, Wh, WT, 12*16384);

  for(int l=0; l<L; ++l){
    const float* inp = (l==0) ? x : (out + (size_t)(l-1)*N*128);
    const float* hl  = h + (size_t)l*N*128;
    k_scale2<<<gew,256,0,stream>>>(inp, hl, dinv, y2, N);
    k_agg<4><<<gagg,256,0,stream>>>(y2, rowp, degi, col, dinv, ax, ah, N);
    for(int k=0;k<3;++k){
      const unsigned short* B1 = WT + (size_t)(l*3+k)*16384;
      const unsigned short* B2 = (k<2) ? (WT + (size_t)(6+l*3+k)*16384) : nullptr;
      k_gemm<<<grows,256,0,stream>>>(ax, (k<2) ? ah : nullptr, B1, B2, Zpre + k*128, 384, N, 0);
    }
    k_zr<<<gew,256,0,stream>>>(Zpre, bx + (size_t)(l*3+1)*128, bh + (size_t)(l*3+1)*128,
                               hl, dinv, yq, N);
    k_agg<2><<<gagg,256,0,stream>>>(yq, rowp, degi, col, dinv, aq, nullptr, N);
    k_gemm<<<grows,256,0,stream>>>(aq, nullptr, WT + (size_t)(6+l*3+2)*16384, nullptr,
                                   Zpre + 256, 384, N, 1);
    k_final<<<gew,256,0,stream>>>(Zpre, bx + (size_t)(l*3)*128, bh + (size_t)(l*3)*128,
                                  bx + (size_t)(l*3+2)*128, bh + (size_t)(l*3+2)*128,
                                  hl, out + (size_t)l*N*128, N);
  }
}

// Round 2
// 728.834 us; speedup vs baseline: 1.4138x; 1.4138x over previous
//
#include <hip/hip_runtime.h>

typedef __attribute__((ext_vector_type(8))) unsigned short us8;
typedef __attribute__((ext_vector_type(4))) unsigned short us4;
typedef __attribute__((ext_vector_type(2))) unsigned short us2;
typedef __attribute__((ext_vector_type(8))) short s8;
typedef __attribute__((ext_vector_type(4))) float f4;

#define DEV static __device__ __forceinline__

DEV float bf2f(unsigned short h){ return __uint_as_float(((unsigned)h)<<16); }
DEV unsigned short f2bf(float f){
  unsigned x = __float_as_uint(f);
  x += 0x7fffu + ((x>>16)&1u);
  return (unsigned short)(x>>16);
}
DEV float sigm(float x){ return 1.f/(1.f + __expf(-x)); }

// ---------------- setup kernels ----------------
__global__ void k_zero_int(int* p, int n){
  int i = blockIdx.x*blockDim.x+threadIdx.x; if(i<n) p[i]=0;
}

__global__ void k_hist(const int* __restrict__ dst, int* __restrict__ degi, int e){
  int i = blockIdx.x*blockDim.x+threadIdx.x;
  if(i<e) atomicAdd(&degi[dst[i]], 1);
}

__global__ void k_dinv(const int* __restrict__ degi, float* __restrict__ dinv, int n){
  int i = blockIdx.x*blockDim.x+threadIdx.x;
  if(i<n) dinv[i] = rsqrtf((float)degi[i] + 1.0f);
}

__global__ void k_scan_part(const int* __restrict__ deg, int* __restrict__ rowp,
                            int* __restrict__ part, int n){
  __shared__ int sd[256];
  int t = threadIdx.x, blk = blockIdx.x;
  int base = blk*1024 + t*4;
  int v[4], tot = 0;
  #pragma unroll
  for(int j=0;j<4;++j){ v[j] = (base+j<n) ? deg[base+j] : 0; tot += v[j]; }
  sd[t] = tot; __syncthreads();
  for(int off=1; off<256; off<<=1){
    int x = (t>=off) ? sd[t-off] : 0;
    __syncthreads();
    sd[t] += x;
    __syncthreads();
  }
  int excl = sd[t] - tot;
  if(t==255) part[blk] = sd[t];
  int run = excl;
  #pragma unroll
  for(int j=0;j<4;++j){ if(base+j<n) rowp[base+j] = run; run += v[j]; }
}

__global__ void k_scan_top(int* part, int nb){
  if(threadIdx.x==0 && blockIdx.x==0){
    int run = 0;
    for(int i=0;i<nb;++i){ int v = part[i]; part[i] = run; run += v; }
  }
}

__global__ void k_scan_add(int* __restrict__ rowp, const int* __restrict__ part, int n){
  int blk = blockIdx.x, t = threadIdx.x;
  int add = part[blk];
  int base = blk*1024 + t*4;
  #pragma unroll
  for(int j=0;j<4;++j) if(base+j<n) rowp[base+j] += add;
}

__global__ void k_fill(const int* __restrict__ src, const int* __restrict__ dst,
                       const int* __restrict__ rowp, int* __restrict__ cnt,
                       int* __restrict__ col, int e){
  int i = blockIdx.x*blockDim.x+threadIdx.x;
  if(i<e){
    int d = dst[i];
    int pos = rowp[d] + atomicAdd(&cnt[d],1);
    col[pos] = src[i];
  }
}

// transpose + bf16-cast the 12 weight matrices: WT[m][j][k] = W[m][k][j]
__global__ void k_prepw(const float* __restrict__ Wx, const float* __restrict__ Wh,
                        unsigned short* __restrict__ WT, int total){
  int i = blockIdx.x*blockDim.x+threadIdx.x;
  if(i>=total) return;
  int m = i >> 14;
  int rem = i & 16383;
  int j = rem >> 7;     // output column
  int k = rem & 127;    // k index
  const float* W = (m<6) ? (Wx + (size_t)m*16384) : (Wh + (size_t)(m-6)*16384);
  WT[(size_t)m*16384 + rem] = f2bf(W[(size_t)k*128 + j]);
}

// ---------------- per-layer kernels ----------------
// y2[n,0:128] = bf16(dinv[n]*inp[n]);  y2[n,128:256] = bf16(dinv[n]*h_l[n])
__global__ void k_scale2(const float* __restrict__ inp, const float* __restrict__ hl,
                         const float* __restrict__ dinv, unsigned short* __restrict__ y2, int n){
  int i = blockIdx.x*blockDim.x+threadIdx.x;
  if(i >= n*32) return;
  int node = i>>5, d0 = (i&31)*4;
  float dv = dinv[node];
  f4 a = *(const f4*)(inp + (size_t)node*128 + d0);
  f4 b = *(const f4*)(hl  + (size_t)node*128 + d0);
  us4 wa, wb;
  #pragma unroll
  for(int j=0;j<4;++j){ wa[j] = f2bf(dv*a[j]); wb[j] = f2bf(dv*b[j]); }
  *(us4*)(y2 + (size_t)node*256 + d0)       = wa;
  *(us4*)(y2 + (size_t)node*256 + 128 + d0) = wb;
}

// CSR aggregation: out = bf16( dinv[n] * ( y[n] + sum_{src->n} y[src] ) )
// NV = bf16 elems per lane (2 -> D=128, 4 -> D=256 split into out0/out1)
// Unrolled gather: keep U independent row loads in flight per wave.
template<int NV>
__global__ __launch_bounds__(256) void k_agg(const unsigned short* __restrict__ y,
    const int* __restrict__ rowp, const int* __restrict__ degi, const int* __restrict__ col,
    const float* __restrict__ dinv, unsigned short* __restrict__ out0,
    unsigned short* __restrict__ out1, int n)
{
  constexpr int D = NV*64;
  constexpr int U = (NV==2) ? 8 : 4;
  int lane = threadIdx.x & 63;
  int node = blockIdx.x*4 + (threadIdx.x>>6);
  if(node >= n) return;
  const unsigned short* ybase = y + (size_t)lane*NV;
  float acc[NV];
  {
    const unsigned short* p = ybase + (size_t)node*D;
    if constexpr(NV==2){ us2 v = *(const us2*)p; acc[0]=bf2f(v[0]); acc[1]=bf2f(v[1]); }
    else { us4 v = *(const us4*)p;
      #pragma unroll
      for(int j=0;j<4;++j) acc[j]=bf2f(v[j]); }
  }
  int start = rowp[node];
  int cnt = degi[node];
  int i = 0;
  for(; i + U <= cnt; i += U){
    int s[U];
    #pragma unroll
    for(int u=0;u<U;++u) s[u] = col[start+i+u];
    if constexpr(NV==2){
      us2 v[U];
      #pragma unroll
      for(int u=0;u<U;++u) v[u] = *(const us2*)(ybase + (size_t)s[u]*D);
      #pragma unroll
      for(int u=0;u<U;++u){ acc[0]+=bf2f(v[u][0]); acc[1]+=bf2f(v[u][1]); }
    } else {
      us4 v[U];
      #pragma unroll
      for(int u=0;u<U;++u) v[u] = *(const us4*)(ybase + (size_t)s[u]*D);
      #pragma unroll
      for(int u=0;u<U;++u){
        #pragma unroll
        for(int j=0;j<4;++j) acc[j]+=bf2f(v[u][j]);
      }
    }
  }
  for(; i<cnt; ++i){
    int s = col[start+i];
    const unsigned short* p = ybase + (size_t)s*D;
    if constexpr(NV==2){ us2 v = *(const us2*)p; acc[0]+=bf2f(v[0]); acc[1]+=bf2f(v[1]); }
    else { us4 v = *(const us4*)p;
      #pragma unroll
      for(int j=0;j<4;++j) acc[j]+=bf2f(v[j]); }
  }
  float dv = dinv[node];
  if constexpr(NV==2){
    us2 w; w[0]=f2bf(acc[0]*dv); w[1]=f2bf(acc[1]*dv);
    *(us2*)(out0 + (size_t)node*128 + lane*2) = w;
  } else {
    us4 w;
    #pragma unroll
    for(int j=0;j<4;++j) w[j]=f2bf(acc[j]*dv);
    int c = lane*4;
    unsigned short* o = (c<128) ? (out0 + (size_t)node*128 + c)
                                : (out1 + (size_t)node*128 + (c-128));
    *(us4*)o = w;
  }
}

// C[brow:brow+128, 0:128] (+)= A1@B1 (+ A2@B2), bf16 MFMA, fp32 out, ldc stride.
__global__ __launch_bounds__(256) void k_gemm(const unsigned short* __restrict__ A1,
    const unsigned short* __restrict__ A2, const unsigned short* __restrict__ B1,
    const unsigned short* __restrict__ B2, float* __restrict__ C, int ldc, int nrows, int accum)
{
  __shared__ unsigned short As[128*136];
  __shared__ unsigned short Bs[128*136];
  const int t = threadIdx.x;
  const int lane = t & 63;
  const int lo = lane & 15, hi = lane >> 4;
  const int wid = t >> 6;
  const int wr = wid >> 1, wc = wid & 1;
  const int brow = blockIdx.x * 128;
  f4 acc[4][4];
  #pragma unroll
  for(int m=0;m<4;++m)
    #pragma unroll
    for(int n=0;n<4;++n) acc[m][n] = (f4)0.f;

  const int nch = A2 ? 2 : 1;
  for(int ch=0; ch<nch; ++ch){
    const unsigned short* A = ch ? A2 : A1;
    const unsigned short* B = ch ? B2 : B1;
    __syncthreads();
    #pragma unroll
    for(int i=0;i<8;++i){
      int c = t + i*256;          // 0..2047 chunks of 8 bf16
      int r = c >> 4, k0 = (c & 15)*8;
      us8 va = (us8)0;
      int gr = brow + r;
      if (gr < nrows) va = *(const us8*)(A + (size_t)gr*128 + k0);
      *(us8*)(&As[r*136 + k0]) = va;
      us8 vb = *(const us8*)(B + (size_t)c*8);
      *(us8*)(&Bs[r*136 + k0]) = vb;
    }
    __syncthreads();
    #pragma unroll
    for(int kk=0;kk<4;++kk){
      s8 af[4], bfr[4];
      #pragma unroll
      for(int m=0;m<4;++m)
        af[m] = *(const s8*)(&As[(wr*64 + m*16 + lo)*136 + kk*32 + hi*8]);
      #pragma unroll
      for(int n=0;n<4;++n)
        bfr[n] = *(const s8*)(&Bs[(wc*64 + n*16 + lo)*136 + kk*32 + hi*8]);
      #pragma unroll
      for(int m=0;m<4;++m)
        #pragma unroll
        for(int n=0;n<4;++n)
          acc[m][n] = __builtin_amdgcn_mfma_f32_16x16x32_bf16(af[m], bfr[n], acc[m][n], 0,0,0);
    }
  }

  const int c0 = wc*64;
  #pragma unroll
  for(int m=0;m<4;++m){
    int rbase = brow + wr*64 + m*16 + hi*4;
    #pragma unroll
    for(int n=0;n<4;++n){
      int colv = c0 + n*16 + lo;
      #pragma unroll
      for(int tt=0;tt<4;++tt){
        int row = rbase + tt;
        if(row < nrows){
          size_t off = (size_t)row*ldc + colv;
          float v = acc[m][n][tt];
          if(accum) v += C[off];
          C[off] = v;
        }
      }
    }
  }
}

// yq = bf16( dinv * sigmoid(rpre + bxr + bhr) * h_l )
__global__ void k_zr(const float* __restrict__ Zpre, const float* __restrict__ bxr,
                     const float* __restrict__ bhr, const float* __restrict__ hl,
                     const float* __restrict__ dinv, unsigned short* __restrict__ yq, int n){
  int i = blockIdx.x*blockDim.x+threadIdx.x;
  if(i >= n*32) return;
  int node = i>>5, d0 = (i&31)*4;
  f4 rp = *(const f4*)(Zpre + (size_t)node*384 + 128 + d0);
  f4 hh = *(const f4*)(hl + (size_t)node*128 + d0);
  float dv = dinv[node];
  us4 w;
  #pragma unroll
  for(int j=0;j<4;++j){
    float r = sigm(rp[j] + bxr[d0+j] + bhr[d0+j]);
    w[j] = f2bf(dv * r * hh[j]);
  }
  *(us4*)(yq + (size_t)node*128 + d0) = w;
}

// out = z*h + (1-z)*tanh(htpre),  z = sigmoid(zpre)
__global__ void k_final(const float* __restrict__ Zpre, const float* __restrict__ bx0,
                        const float* __restrict__ bh0, const float* __restrict__ bx2,
                        const float* __restrict__ bh2, const float* __restrict__ hl,
                        float* __restrict__ out, int n){
  int i = blockIdx.x*blockDim.x+threadIdx.x;
  if(i >= n*32) return;
  int node = i>>5, d0 = (i&31)*4;
  f4 zp = *(const f4*)(Zpre + (size_t)node*384 + d0);
  f4 hp = *(const f4*)(Zpre + (size_t)node*384 + 256 + d0);
  f4 hh = *(const f4*)(hl + (size_t)node*128 + d0);
  f4 o;
  #pragma unroll
  for(int j=0;j<4;++j){
    float z  = sigm(zp[j] + bx0[d0+j] + bh0[d0+j]);
    float ht = tanhf(hp[j] + bx2[d0+j] + bh2[d0+j]);
    o[j] = z*hh[j] + (1.f - z)*ht;
  }
  *(f4*)(out + (size_t)node*128 + d0) = o;
}

extern "C" void kernel_launch(void* const* d_in, const int* in_sizes, int n_in,
                              void* d_out, int out_size, void* d_ws, size_t ws_size,
                              hipStream_t stream){
  const float* x  = (const float*)d_in[0];
  const int*   ei = (const int*)d_in[1];
  const float* h  = (const float*)d_in[2];
  const float* Wx = (const float*)d_in[3];
  const float* bx = (const float*)d_in[4];
  const float* Wh = (const float*)d_in[5];
  const float* bh = (const float*)d_in[6];
  float* out = (float*)d_out;

  const int N = in_sizes[0] / 128;
  const int E = in_sizes[1] / 2;
  const int L = in_sizes[2] / in_sizes[0];
  const int* src = ei;
  const int* dst = ei + E;

  char* w = (char*)d_ws;
  auto alloc = [&](size_t b)->char*{ char* p = w; w += (b + 255) & ~(size_t)255; return p; };
  int* degi = (int*)alloc((size_t)2*N*sizeof(int)); int* cnt = degi + N;
  int* rowp = (int*)alloc((size_t)N*sizeof(int));
  int* part = (int*)alloc(256*sizeof(int));
  int* col  = (int*)alloc((size_t)E*sizeof(int));
  float* dinv = (float*)alloc((size_t)N*sizeof(float));
  unsigned short* WT = (unsigned short*)alloc((size_t)12*16384*sizeof(short));
  unsigned short* y2 = (unsigned short*)alloc((size_t)N*256*sizeof(short));
  unsigned short* ax = (unsigned short*)alloc((size_t)N*128*sizeof(short));
  unsigned short* ah = (unsigned short*)alloc((size_t)N*128*sizeof(short));
  unsigned short* yq = (unsigned short*)alloc((size_t)N*128*sizeof(short));
  unsigned short* aq = (unsigned short*)alloc((size_t)N*128*sizeof(short));
  float* Zpre = (float*)alloc((size_t)N*384*sizeof(float));

  const int NB = (N + 1023)/1024;
  const int gE = (E + 255)/256;
  const int gN = (N + 255)/256;
  const int gew = (N*32 + 255)/256;
  const int gagg = (N + 3)/4;
  const int grows = (N + 127)/128;

  k_zero_int<<<(2*N+255)/256,256,0,stream>>>(degi, 2*N);
  k_hist<<<gE,256,0,stream>>>(dst, degi, E);
  k_dinv<<<gN,256,0,stream>>>(degi, dinv, N);
  k_scan_part<<<NB,256,0,stream>>>(degi, rowp, part, N);
  k_scan_top<<<1,64,0,stream>>>(part, NB);
  k_scan_add<<<NB,256,0,stream>>>(rowp, part, N);
  k_fill<<<gE,256,0,stream>>>(src, dst, rowp, cnt, col, E);
  k_prepw<<<(12*16384+255)/256,256,0,stream>>>(Wx, Wh, WT, 12*16384);

  for(int l=0; l<L; ++l){
    const float* inp = (l==0) ? x : (out + (size_t)(l-1)*N*128);
    const float* hl  = h + (size_t)l*N*128;
    k_scale2<<<gew,256,0,stream>>>(inp, hl, dinv, y2, N);
    k_agg<4><<<gagg,256,0,stream>>>(y2, rowp, degi, col, dinv, ax, ah, N);
    for(int k=0;k<3;++k){
      const unsigned short* B1 = WT + (size_t)(l*3+k)*16384;
      const unsigned short* B2 = (k<2) ? (WT + (size_t)(6+l*3+k)*16384) : nullptr;
      k_gemm<<<grows,256,0,stream>>>(ax, (k<2) ? ah : nullptr, B1, B2, Zpre + k*128, 384, N, 0);
    }
    k_zr<<<gew,256,0,stream>>>(Zpre, bx + (size_t)(l*3+1)*128, bh + (size_t)(l*3+1)*128,
                               hl, dinv, yq, N);
    k_agg<2><<<gagg,256,0,stream>>>(yq, rowp, degi, col, dinv, aq, nullptr, N);
    k_gemm<<<grows,256,0,stream>>>(aq, nullptr, WT + (size_t)(6+l*3+2)*16384, nullptr,
                                   Zpre + 256, 384, N, 1);
    k_final<<<gew,256,0,stream>>>(Zpre, bx + (size_t)(l*3)*128, bh + (size_t)(l*3)*128,
                                  bx + (size_t)(l*3+2)*128, bh + (size_t)(l*3+2)*128,
                                  hl, out + (size_t)l*N*128, N);
  }
}